// Round 20
// baseline (165.187 us; speedup 1.0000x reference)
//
#include <hip/hip_runtime.h>
#include <hip/hip_bf16.h>

typedef __attribute__((ext_vector_type(8))) __bf16 bf16x8;
typedef __attribute__((ext_vector_type(4))) float f32x4;
typedef __attribute__((ext_vector_type(16))) float f32x16;
typedef __attribute__((ext_vector_type(4))) unsigned short u16x4;
typedef __attribute__((ext_vector_type(8))) unsigned short u16x8;
typedef __attribute__((ext_vector_type(4))) unsigned int u32x4;
typedef unsigned short u16;

#define MFMA16 __builtin_amdgcn_mfma_f32_16x16x32_bf16
#define MFMA32 __builtin_amdgcn_mfma_f32_32x32x16_bf16

#if __has_builtin(__builtin_amdgcn_exp2f)
#define EXP2F __builtin_amdgcn_exp2f
#else
#define EXP2F(x) __expf((x) * 0.69314718056f)
#endif

__device__ inline u16 f32_to_bf16_bits(float f) {      // RNE (weights/outputs)
    unsigned u = __builtin_bit_cast(unsigned, f);
    unsigned r = u + 0x7FFFu + ((u >> 16) & 1u);
    return (u16)(r >> 16);
}

__device__ inline void g2l16(const void* g, void* l) {
    __builtin_amdgcn_global_load_lds(
        (const __attribute__((address_space(1))) unsigned int*)g,
        (__attribute__((address_space(3))) unsigned int*)l,
        16, 0, 0);
}

__device__ inline float red32_max(float x) { return fmaxf(x, __shfl_xor(x, 32)); }
__device__ inline float red32_sum(float x) { return x + __shfl_xor(x, 32); }

// ---------------- convert: f32 -> bf16, 8 elem/thread (16B stores) ----------------
__global__ void cvt_bf16_kernel(const float* __restrict__ in, u16* __restrict__ out, int n) {
    int i = (blockIdx.x * 256 + threadIdx.x) * 8;
    if (i >= n) return;
    f32x4 v0 = *(const f32x4*)&in[i];
    f32x4 v1 = *(const f32x4*)&in[i + 4];
    u16x8 r;
#pragma unroll
    for (int j = 0; j < 4; ++j) {
        r[j] = f32_to_bf16_bits(v0[j]);
        r[j + 4] = f32_to_bf16_bits(v1[j]);
    }
    *(u16x8*)&out[i] = r;
}

// ---------------- merged transpose+convert: both W matrices in one launch ----------------
// W[K][N] f32 -> WT[N][K] bf16. Blocks [0, N1/64) handle W1, rest W2.
__global__ __launch_bounds__(256) void cvt_t2_kernel(
    const float* __restrict__ W1, u16* __restrict__ WT1, int N1,
    const float* __restrict__ W2, u16* __restrict__ WT2, int N2, int K)
{
    int bx = blockIdx.x;
    const float* W; u16* WT; int N;
    const int nb1 = N1 >> 6;
    if (bx < nb1) { W = W1; WT = WT1; N = N1; }
    else          { W = W2; WT = WT2; N = N2; bx -= nb1; }
    const int w = threadIdx.x >> 6, l = threadIdx.x & 63;
    const int n = bx * 64 + l;
    const int k0 = blockIdx.y * 32 + w * 8;
    u16x8 r;
#pragma unroll
    for (int i = 0; i < 8; ++i)
        r[i] = f32_to_bf16_bits(W[(size_t)(k0 + i) * N + n]);
    *(u16x8*)&WT[(size_t)n * K + k0] = r;
}

// ---------------- GEMM v2 (proven R10/R13/R15): 128x128, BK=32, 3-deep counted vmcnt ----------------
template <int STORE_BF16>
__global__ __launch_bounds__(256) void gemm_nt(
    const u16* __restrict__ A, const u16* __restrict__ BT,
    const float* __restrict__ bias, void* __restrict__ Cv,
    int M, int N, int K, int qcols, float qscale, int nbx)
{
    __shared__ __align__(16) u16 SM[24576];   // 3 sets x (A[128][32] | B[128][32])
    const int tid = threadIdx.x;
    const int w = tid >> 6, l = tid & 63;
    const int lr = l & 15, lh = l >> 4;
    const int wr = (w >> 1) * 64, wc = (w & 1) * 64;

    const int nwg = gridDim.x;
    const int swz = (blockIdx.x & 7) * (nwg >> 3) + (blockIdx.x >> 3);
    const int m0 = (swz / nbx) * 128;
    const int n0 = (swz % nbx) * 128;

    const int NT = K >> 5;

    const int f0 = tid, f1 = 256 + tid;
    const int r0 = f0 >> 2, r1 = f1 >> 2;
    const int cs0 = ((f0 & 3) ^ ((r0 >> 1) & 3)) * 8;
    const int cs1 = ((f1 & 3) ^ ((r1 >> 1) & 3)) * 8;
    const size_t arow0 = (size_t)(m0 + r0) * K, arow1 = (size_t)(m0 + r1) * K;
    const size_t brow0 = (size_t)(n0 + r0) * K, brow1 = (size_t)(n0 + r1) * K;

#define STAGE_TILE(t, set)                                                     \
    do {                                                                       \
        const int kk_ = (t) * 32;                                              \
        u16* dst_ = SM + (set) * 8192 + w * 512;                               \
        g2l16(A + arow0 + kk_ + cs0, dst_);                                    \
        g2l16(BT + brow0 + kk_ + cs0, dst_ + 4096);                            \
        g2l16(A + arow1 + kk_ + cs1, dst_ + 2048);                             \
        g2l16(BT + brow1 + kk_ + cs1, dst_ + 4096 + 2048);                     \
    } while (0)

    f32x4 acc[4][4];
#pragma unroll
    for (int m = 0; m < 4; ++m)
#pragma unroll
        for (int n = 0; n < 4; ++n) acc[m][n] = (f32x4)(0.0f);

    STAGE_TILE(0, 0);
    STAGE_TILE(1, 1);
    asm volatile("s_waitcnt vmcnt(4) lgkmcnt(0)\n\ts_barrier" ::: "memory");

    const int csw = (lr >> 1) & 3;
    int s0 = 0, s2 = 2;
    for (int t = 0; t < NT; ++t) {
        if (t + 2 < NT) STAGE_TILE(t + 2, s2);

        const u16* As = SM + s0 * 8192;
        const u16* Bs = As + 4096;
        bf16x8 af[4], bfr[4];
#pragma unroll
        for (int m = 0; m < 4; ++m)
            af[m] = *(const bf16x8*)&As[(wr + m * 16 + lr) * 32 + ((lh ^ csw) << 3)];
#pragma unroll
        for (int n = 0; n < 4; ++n)
            bfr[n] = *(const bf16x8*)&Bs[(wc + n * 16 + lr) * 32 + ((lh ^ csw) << 3)];
        __builtin_amdgcn_s_setprio(1);
#pragma unroll
        for (int m = 0; m < 4; ++m)
#pragma unroll
            for (int n = 0; n < 4; ++n)
                acc[m][n] = MFMA16(af[m], bfr[n], acc[m][n], 0, 0, 0);
        __builtin_amdgcn_s_setprio(0);

        if (t + 2 < NT)
            asm volatile("s_waitcnt vmcnt(4) lgkmcnt(0)\n\ts_barrier" ::: "memory");
        else if (t + 1 < NT)
            asm volatile("s_waitcnt vmcnt(0) lgkmcnt(0)\n\ts_barrier" ::: "memory");

        s0 = (s0 == 2) ? 0 : s0 + 1;
        s2 = (s2 == 2) ? 0 : s2 + 1;
    }
#undef STAGE_TILE

#pragma unroll
    for (int m = 0; m < 4; ++m) {
        int row = m0 + wr + m * 16 + lh * 4;
#pragma unroll
        for (int n = 0; n < 4; ++n) {
            int col = n0 + wc + n * 16 + lr;
            float bs = bias[col];
            float sc = (col < qcols) ? qscale : 1.0f;
#pragma unroll
            for (int j = 0; j < 4; ++j) {
                float v = (acc[m][n][j] + bs) * sc;
                if (STORE_BF16)
                    ((u16*)Cv)[(size_t)(row + j) * N + col] = f32_to_bf16_bits(v);
                else
                    ((float*)Cv)[(size_t)(row + j) * N + col] = v;
            }
        }
    }
}

// ---------------- causal flash attention v9 (proven R15): KVBLK=128 ----------------
__global__ __launch_bounds__(512, 1) void attn_kernel(
    const u16* __restrict__ qkv, u16* __restrict__ ctx)
{
    __shared__ __align__(16) u16 SM[32768];  // K 2x8K u16 | V 2x8K u16

    const int bid = blockIdx.x;
    const int xcd = bid & 7, jj = bid >> 3;        // 32 blocks per XCD
    const int bh = xcd * 8 + (jj >> 2);            // 8 heads per XCD (4MB KV = L2)
    const int pr = jj & 3;                         // pair: qt = pr, then 7-pr
    const int b = bh >> 4, h = bh & 15;
    const size_t rowbase = (size_t)b * 2048;
    const int tid = threadIdx.x, w = tid >> 6, l = tid & 63;
    const int lq = l & 31, lk = l >> 5;            // q-col owner, k-half

    const int rsub = l >> 3;                       // row within 8-row group
    const int cstage = l & 7;
    const int kchunk = cstage ^ rsub;              // inverse-swizzle src (key=row&7)

    bf16x8 vreg[2];

#pragma unroll
    for (int pass = 0; pass < 2; ++pass) {
        const int qt = pass ? (7 - pr) : pr;
        const int q0 = qt * 256;
        const int nt = 2 * qt + 2;                 // 128-wide K/V tiles
        const int qbase = q0 + w * 32;

        const u16* qp = qkv + (rowbase + qbase + lq) * 3072 + h * 64 + lk * 8;
        bf16x8 qf[4];
#pragma unroll
        for (int j = 0; j < 4; ++j) qf[j] = *(const bf16x8*)(qp + j * 16);

        f32x16 ot[2];
#pragma unroll
        for (int dt = 0; dt < 2; ++dt) ot[dt] = (f32x16)(0.0f);
        float m_run = -3e38f, l_run = 0.0f;

        // ---- prologue: stage tile 0 ----
        __syncthreads();
#pragma unroll
        for (int p = 0; p < 2; ++p) {
            const int r = w * 16 + p * 8 + rsub;
            g2l16(qkv + (rowbase + r) * 3072 + 1024 + h * 64 + kchunk * 8,
                  SM + w * 1024 + p * 512);
            vreg[p] = *(const bf16x8*)(qkv + (rowbase + r) * 3072 + 2048 + h * 64 + cstage * 8);
        }
        asm volatile("s_waitcnt vmcnt(0)" ::: "memory");
#pragma unroll
        for (int p = 0; p < 2; ++p) {
            const int r = w * 16 + p * 8 + rsub;
#pragma unroll
            for (int i = 0; i < 8; ++i) {
                const int d = cstage * 8 + i;
                SM[16384 + ((d * 128 + r) ^ (((i ^ cstage) & 7) << 3))] = ((const u16*)&vreg[p])[i];
            }
        }
        __syncthreads();

        for (int t = 0; t < nt; ++t) {
            const int c = t & 1;
            const int kb = t * 128;
            u16* const Kb = SM + (c ? 8192 : 0);
            u16* const Vb = SM + 16384 + (c ? 8192 : 0);

            if (t + 1 < nt) {   // issue next-tile staging first
                const int kb2 = kb + 128;
#pragma unroll
                for (int p = 0; p < 2; ++p) {
                    const int r = w * 16 + p * 8 + rsub;
                    g2l16(qkv + (rowbase + kb2 + r) * 3072 + 1024 + h * 64 + kchunk * 8,
                          SM + (c ? 0 : 8192) + w * 1024 + p * 512);
                    vreg[p] = *(const bf16x8*)(qkv + (rowbase + kb2 + r) * 3072 + 2048 + h * 64 + cstage * 8);
                }
            }

            if (kb <= qbase + 31) {   // strip visible
                bf16x8 kf[4][4];
#pragma unroll
                for (int kt = 0; kt < 4; ++kt)
#pragma unroll
                    for (int j = 0; j < 4; ++j)
                        kf[kt][j] = *(const bf16x8*)&Kb[((kt * 32 + lq) * 64 + j * 16 + lk * 8) ^ ((lq & 7) << 3)];

                f32x16 sf[4];
                __builtin_amdgcn_s_setprio(1);
#pragma unroll
                for (int kt = 0; kt < 4; ++kt) {
                    f32x16 z = (f32x16)(0.0f);
#pragma unroll
                    for (int j = 0; j < 4; ++j) z = MFMA32(kf[kt][j], qf[j], z, 0, 0, 0);
                    sf[kt] = z;
                }
                __builtin_amdgcn_s_setprio(0);

                float mt = -3e38f;
                if (kb + 127 > qbase) {         // diagonal region: causal mask
                    const int qrow = qbase + lq;
#pragma unroll
                    for (int kt = 0; kt < 4; ++kt)
#pragma unroll
                        for (int r = 0; r < 16; ++r) {
                            const int key = kb + kt * 32 + (r & 3) + 8 * (r >> 2) + 4 * lk;
                            float v = sf[kt][r];
                            if (key > qrow) v = -3e38f;
                            sf[kt][r] = v;
                            mt = fmaxf(mt, v);
                        }
                } else {
#pragma unroll
                    for (int kt = 0; kt < 4; ++kt)
#pragma unroll
                        for (int r = 0; r < 16; ++r) mt = fmaxf(mt, sf[kt][r]);
                }
                mt = red32_max(mt);

                const bool defer = __all(mt <= m_run + 16.0f);
                float mn = m_run;
                if (!defer) {
                    mn = fmaxf(m_run, mt);
                    const float alpha = EXP2F(m_run - mn);
                    m_run = mn;
                    l_run *= alpha;
#pragma unroll
                    for (int dt = 0; dt < 2; ++dt)
#pragma unroll
                        for (int r = 0; r < 16; ++r) ot[dt][r] *= alpha;
                }
                float rs = 0.0f;
#pragma unroll
                for (int kt = 0; kt < 4; ++kt)
#pragma unroll
                    for (int r = 0; r < 16; ++r) {
                        const float pp = EXP2F(sf[kt][r] - mn);
                        sf[kt][r] = pp;
                        rs += pp;
                    }
                l_run += red32_sum(rs);

                unsigned pc[4][4][2];
#pragma unroll
                for (int kt = 0; kt < 4; ++kt)
#pragma unroll
                    for (int rg = 0; rg < 4; ++rg) {
                        unsigned d0, d1;
                        asm("v_cvt_pk_bf16_f32 %0, %1, %2"
                            : "=v"(d0) : "v"((float)sf[kt][rg * 4 + 0]), "v"((float)sf[kt][rg * 4 + 1]));
                        asm("v_cvt_pk_bf16_f32 %0, %1, %2"
                            : "=v"(d1) : "v"((float)sf[kt][rg * 4 + 2]), "v"((float)sf[kt][rg * 4 + 3]));
                        pc[kt][rg][0] = d0;
                        pc[kt][rg][1] = d1;
                    }

                __builtin_amdgcn_s_setprio(1);
#pragma unroll
                for (int kt = 0; kt < 4; ++kt)
#pragma unroll
                    for (int hh = 0; hh < 2; ++hh) {
                        unsigned a0 = pc[kt][2 * hh][0], a1 = pc[kt][2 * hh][1];
                        unsigned b0 = pc[kt][2 * hh + 1][0], b1 = pc[kt][2 * hh + 1][1];
                        asm("v_permlane32_swap_b32 %0, %1" : "+v"(a0), "+v"(b0));
                        asm("v_permlane32_swap_b32 %0, %1" : "+v"(a1), "+v"(b1));
                        u32x4 wv = {a0, a1, b0, b1};
                        const bf16x8 pb = __builtin_bit_cast(bf16x8, wv);
                        const int k0 = 2 * kt + hh;
#pragma unroll
                        for (int dt = 0; dt < 2; ++dt) {
                            const int d = dt * 32 + lq;
                            const int vswz = ((d & 7) ^ (d >> 3)) & 7;
                            const bf16x8 vf = *(const bf16x8*)&Vb[((d * 128) + (k0 * 16 + lk * 8)) ^ (vswz << 3)];
                            ot[dt] = MFMA32(vf, pb, ot[dt], 0, 0, 0);
                        }
                    }
                __builtin_amdgcn_s_setprio(0);
            }

            asm volatile("s_waitcnt vmcnt(0)" ::: "memory");
            if (t + 1 < nt) {
                u16* const Vn = SM + 16384 + (c ? 0 : 8192);
#pragma unroll
                for (int p = 0; p < 2; ++p) {
                    const int r = w * 16 + p * 8 + rsub;
#pragma unroll
                    for (int i = 0; i < 8; ++i) {
                        const int d = cstage * 8 + i;
                        Vn[((d * 128 + r) ^ (((i ^ cstage) & 7) << 3))] = ((const u16*)&vreg[p])[i];
                    }
                }
            }
            __syncthreads();   // single barrier per tile-step
        }

        // ---- epilogue: O^T -> LDS transpose -> coalesced bf16 stores ----
        u16* const out_l = SM + w * 2176;   // [32][68] per wave (private region)
        const float inv = 1.0f / l_run;
#pragma unroll
        for (int dt = 0; dt < 2; ++dt)
#pragma unroll
            for (int r = 0; r < 16; ++r) {
                const int d = dt * 32 + (r & 3) + 8 * (r >> 2) + 4 * lk;
                out_l[lq * 68 + d] = f32_to_bf16_bits(ot[dt][r] * inv);
            }
#pragma unroll
        for (int rr = 0; rr < 4; ++rr) {
            const int row = rr * 8 + (l >> 3);
            const bf16x8 v = *(const bf16x8*)&out_l[row * 68 + (l & 7) * 8];
            *(bf16x8*)(ctx + (rowbase + qbase + row) * 1024 + h * 64 + (l & 7) * 8) = v;
        }
    }
}

extern "C" void kernel_launch(void* const* d_in, const int* in_sizes, int n_in,
                              void* d_out, int out_size, void* d_ws, size_t ws_size,
                              hipStream_t stream) {
    const float* x      = (const float*)d_in[0];
    const float* W_qkv  = (const float*)d_in[1];
    const float* b_qkv  = (const float*)d_in[2];
    const float* W_o    = (const float*)d_in[3];
    const float* b_o    = (const float*)d_in[4];
    float* out = (float*)d_out;

    const int M = 4 * 2048;     // 8192 rows
    const int C = 1024;
    u16* qkv   = (u16*)d_ws;                       // [8192][3072]
    u16* xb    = qkv   + (size_t)M * 3 * C;        // [8192][1024]
    u16* wqkvt = xb    + (size_t)M * C;            // [3072][1024]
    u16* ctx   = wqkvt + (size_t)3 * C * C;        // [8192][1024]
    u16* wot   = ctx   + (size_t)M * C;            // [1024][1024]

    const float SCQ = 0.125f * 1.44269504089f;     // 1/sqrt(64) * log2(e)

    cvt_bf16_kernel<<<(M * C) / (256 * 8), 256, 0, stream>>>(x, xb, M * C);
    cvt_t2_kernel<<<dim3(3 * C / 64 + C / 64, C / 32), 256, 0, stream>>>(
        W_qkv, wqkvt, 3 * C, W_o, wot, C, C);

    // QKV projection: v2 (proven), grid 24*64=1536 (%8==0), nbx=24
    gemm_nt<1><<<(3 * C / 128) * (M / 128), 256, 0, stream>>>(xb, wqkvt, b_qkv, qkv,
                                                              M, 3 * C, C, C, SCQ, 3 * C / 128);

    attn_kernel<<<256, 512, 0, stream>>>(qkv, ctx);

    // output projection: v2, grid 8*64=512, nbx=8
    gemm_nt<0><<<(C / 128) * (M / 128), 256, 0, stream>>>(ctx, wot, b_o, out,
                                                          M, C, C, 0, 1.0f, C / 128);
}

// Round 21
// 162.271 us; speedup vs baseline: 1.0180x; 1.0180x over previous
//
#include <hip/hip_runtime.h>
#include <hip/hip_bf16.h>

typedef __attribute__((ext_vector_type(8))) __bf16 bf16x8;
typedef __attribute__((ext_vector_type(4))) float f32x4;
typedef __attribute__((ext_vector_type(16))) float f32x16;
typedef __attribute__((ext_vector_type(4))) unsigned short u16x4;
typedef __attribute__((ext_vector_type(8))) unsigned short u16x8;
typedef __attribute__((ext_vector_type(4))) unsigned int u32x4;
typedef unsigned short u16;

#define MFMA16 __builtin_amdgcn_mfma_f32_16x16x32_bf16
#define MFMA32 __builtin_amdgcn_mfma_f32_32x32x16_bf16

#if __has_builtin(__builtin_amdgcn_exp2f)
#define EXP2F __builtin_amdgcn_exp2f
#else
#define EXP2F(x) __expf((x) * 0.69314718056f)
#endif

__device__ inline u16 f32_to_bf16_bits(float f) {      // RNE (weights/outputs)
    unsigned u = __builtin_bit_cast(unsigned, f);
    unsigned r = u + 0x7FFFu + ((u >> 16) & 1u);
    return (u16)(r >> 16);
}

__device__ inline void g2l16(const void* g, void* l) {
    __builtin_amdgcn_global_load_lds(
        (const __attribute__((address_space(1))) unsigned int*)g,
        (__attribute__((address_space(3))) unsigned int*)l,
        16, 0, 0);
}

__device__ inline float red32_max(float x) { return fmaxf(x, __shfl_xor(x, 32)); }
__device__ inline float red32_sum(float x) { return x + __shfl_xor(x, 32); }

// ---------------- convert: f32 -> bf16, 8 elem/thread (16B stores) ----------------
__global__ void cvt_bf16_kernel(const float* __restrict__ in, u16* __restrict__ out, int n) {
    int i = (blockIdx.x * 256 + threadIdx.x) * 8;
    if (i >= n) return;
    f32x4 v0 = *(const f32x4*)&in[i];
    f32x4 v1 = *(const f32x4*)&in[i + 4];
    u16x8 r;
#pragma unroll
    for (int j = 0; j < 4; ++j) {
        r[j] = f32_to_bf16_bits(v0[j]);
        r[j + 4] = f32_to_bf16_bits(v1[j]);
    }
    *(u16x8*)&out[i] = r;
}

// ---------------- merged transpose+convert: both W matrices in one launch ----------------
__global__ __launch_bounds__(256) void cvt_t2_kernel(
    const float* __restrict__ W1, u16* __restrict__ WT1, int N1,
    const float* __restrict__ W2, u16* __restrict__ WT2, int N2, int K)
{
    int bx = blockIdx.x;
    const float* W; u16* WT; int N;
    const int nb1 = N1 >> 6;
    if (bx < nb1) { W = W1; WT = WT1; N = N1; }
    else          { W = W2; WT = WT2; N = N2; bx -= nb1; }
    const int w = threadIdx.x >> 6, l = threadIdx.x & 63;
    const int n = bx * 64 + l;
    const int k0 = blockIdx.y * 32 + w * 8;
    u16x8 r;
#pragma unroll
    for (int i = 0; i < 8; ++i)
        r[i] = f32_to_bf16_bits(W[(size_t)(k0 + i) * N + n]);
    *(u16x8*)&WT[(size_t)n * K + k0] = r;
}

// ---------------- GEMM v2 (proven) + L2-supertiled XCD walk ----------------
// 128x128, BK=32, 3-deep counted vmcnt. Block order within each XCD: n-groups
// of 8 x (8m x 8n) supertiles -> per-group working set A 2MB + B 2MB = 4MB =
// one XCD L2 (was 8.3MB -> B thrash, FETCH 5x ideal). Requires M/128 == 64
// and (N/128) % 8 == 0 (true for both uses: 3072/128=24, 1024/128=8).
template <int STORE_BF16>
__global__ __launch_bounds__(256) void gemm_nt(
    const u16* __restrict__ A, const u16* __restrict__ BT,
    const float* __restrict__ bias, void* __restrict__ Cv,
    int M, int N, int K, int qcols, float qscale, int nbx)
{
    __shared__ __align__(16) u16 SM[24576];   // 3 sets x (A[128][32] | B[128][32])
    const int tid = threadIdx.x;
    const int w = tid >> 6, l = tid & 63;
    const int lr = l & 15, lh = l >> 4;
    const int wr = (w >> 1) * 64, wc = (w & 1) * 64;

    // supertiled XCD-local mapping: xcd owns m-tiles [xcd*8, xcd*8+8);
    // within-xcd id j: group g = j>>6 picks 8 n-tiles; r = j&63 -> 8m x 8n.
    const int xcd = blockIdx.x & 7;
    const int j = blockIdx.x >> 3;
    const int g = j >> 6;
    const int r = j & 63;
    const int m0 = (xcd * 8 + (r >> 3)) * 128;
    const int n0 = (g * 8 + (r & 7)) * 128;
    (void)nbx;

    const int NT = K >> 5;

    const int f0 = tid, f1 = 256 + tid;
    const int r0 = f0 >> 2, r1 = f1 >> 2;
    const int cs0 = ((f0 & 3) ^ ((r0 >> 1) & 3)) * 8;
    const int cs1 = ((f1 & 3) ^ ((r1 >> 1) & 3)) * 8;
    const size_t arow0 = (size_t)(m0 + r0) * K, arow1 = (size_t)(m0 + r1) * K;
    const size_t brow0 = (size_t)(n0 + r0) * K, brow1 = (size_t)(n0 + r1) * K;

#define STAGE_TILE(t, set)                                                     \
    do {                                                                       \
        const int kk_ = (t) * 32;                                              \
        u16* dst_ = SM + (set) * 8192 + w * 512;                               \
        g2l16(A + arow0 + kk_ + cs0, dst_);                                    \
        g2l16(BT + brow0 + kk_ + cs0, dst_ + 4096);                            \
        g2l16(A + arow1 + kk_ + cs1, dst_ + 2048);                             \
        g2l16(BT + brow1 + kk_ + cs1, dst_ + 4096 + 2048);                     \
    } while (0)

    f32x4 acc[4][4];
#pragma unroll
    for (int m = 0; m < 4; ++m)
#pragma unroll
        for (int n = 0; n < 4; ++n) acc[m][n] = (f32x4)(0.0f);

    STAGE_TILE(0, 0);
    STAGE_TILE(1, 1);
    asm volatile("s_waitcnt vmcnt(4) lgkmcnt(0)\n\ts_barrier" ::: "memory");

    const int csw = (lr >> 1) & 3;
    int s0 = 0, s2 = 2;
    for (int t = 0; t < NT; ++t) {
        if (t + 2 < NT) STAGE_TILE(t + 2, s2);

        const u16* As = SM + s0 * 8192;
        const u16* Bs = As + 4096;
        bf16x8 af[4], bfr[4];
#pragma unroll
        for (int m = 0; m < 4; ++m)
            af[m] = *(const bf16x8*)&As[(wr + m * 16 + lr) * 32 + ((lh ^ csw) << 3)];
#pragma unroll
        for (int n = 0; n < 4; ++n)
            bfr[n] = *(const bf16x8*)&Bs[(wc + n * 16 + lr) * 32 + ((lh ^ csw) << 3)];
        __builtin_amdgcn_s_setprio(1);
#pragma unroll
        for (int m = 0; m < 4; ++m)
#pragma unroll
            for (int n = 0; n < 4; ++n)
                acc[m][n] = MFMA16(af[m], bfr[n], acc[m][n], 0, 0, 0);
        __builtin_amdgcn_s_setprio(0);

        if (t + 2 < NT)
            asm volatile("s_waitcnt vmcnt(4) lgkmcnt(0)\n\ts_barrier" ::: "memory");
        else if (t + 1 < NT)
            asm volatile("s_waitcnt vmcnt(0) lgkmcnt(0)\n\ts_barrier" ::: "memory");

        s0 = (s0 == 2) ? 0 : s0 + 1;
        s2 = (s2 == 2) ? 0 : s2 + 1;
    }
#undef STAGE_TILE

#pragma unroll
    for (int m = 0; m < 4; ++m) {
        int row = m0 + wr + m * 16 + lh * 4;
#pragma unroll
        for (int n = 0; n < 4; ++n) {
            int col = n0 + wc + n * 16 + lr;
            float bs = bias[col];
            float sc = (col < qcols) ? qscale : 1.0f;
#pragma unroll
            for (int j2 = 0; j2 < 4; ++j2) {
                float v = (acc[m][n][j2] + bs) * sc;
                if (STORE_BF16)
                    ((u16*)Cv)[(size_t)(row + j2) * N + col] = f32_to_bf16_bits(v);
                else
                    ((float*)Cv)[(size_t)(row + j2) * N + col] = v;
            }
        }
    }
}

// ---------------- causal flash attention v9 (proven R15): KVBLK=128 ----------------
__global__ __launch_bounds__(512, 1) void attn_kernel(
    const u16* __restrict__ qkv, u16* __restrict__ ctx)
{
    __shared__ __align__(16) u16 SM[32768];  // K 2x8K u16 | V 2x8K u16

    const int bid = blockIdx.x;
    const int xcd = bid & 7, jj = bid >> 3;        // 32 blocks per XCD
    const int bh = xcd * 8 + (jj >> 2);            // 8 heads per XCD (4MB KV = L2)
    const int pr = jj & 3;                         // pair: qt = pr, then 7-pr
    const int b = bh >> 4, h = bh & 15;
    const size_t rowbase = (size_t)b * 2048;
    const int tid = threadIdx.x, w = tid >> 6, l = tid & 63;
    const int lq = l & 31, lk = l >> 5;            // q-col owner, k-half

    const int rsub = l >> 3;                       // row within 8-row group
    const int cstage = l & 7;
    const int kchunk = cstage ^ rsub;              // inverse-swizzle src (key=row&7)

    bf16x8 vreg[2];

#pragma unroll
    for (int pass = 0; pass < 2; ++pass) {
        const int qt = pass ? (7 - pr) : pr;
        const int q0 = qt * 256;
        const int nt = 2 * qt + 2;                 // 128-wide K/V tiles
        const int qbase = q0 + w * 32;

        const u16* qp = qkv + (rowbase + qbase + lq) * 3072 + h * 64 + lk * 8;
        bf16x8 qf[4];
#pragma unroll
        for (int j = 0; j < 4; ++j) qf[j] = *(const bf16x8*)(qp + j * 16);

        f32x16 ot[2];
#pragma unroll
        for (int dt = 0; dt < 2; ++dt) ot[dt] = (f32x16)(0.0f);
        float m_run = -3e38f, l_run = 0.0f;

        // ---- prologue: stage tile 0 ----
        __syncthreads();
#pragma unroll
        for (int p = 0; p < 2; ++p) {
            const int r = w * 16 + p * 8 + rsub;
            g2l16(qkv + (rowbase + r) * 3072 + 1024 + h * 64 + kchunk * 8,
                  SM + w * 1024 + p * 512);
            vreg[p] = *(const bf16x8*)(qkv + (rowbase + r) * 3072 + 2048 + h * 64 + cstage * 8);
        }
        asm volatile("s_waitcnt vmcnt(0)" ::: "memory");
#pragma unroll
        for (int p = 0; p < 2; ++p) {
            const int r = w * 16 + p * 8 + rsub;
#pragma unroll
            for (int i = 0; i < 8; ++i) {
                const int d = cstage * 8 + i;
                SM[16384 + ((d * 128 + r) ^ (((i ^ cstage) & 7) << 3))] = ((const u16*)&vreg[p])[i];
            }
        }
        __syncthreads();

        for (int t = 0; t < nt; ++t) {
            const int c = t & 1;
            const int kb = t * 128;
            u16* const Kb = SM + (c ? 8192 : 0);
            u16* const Vb = SM + 16384 + (c ? 8192 : 0);

            if (t + 1 < nt) {   // issue next-tile staging first
                const int kb2 = kb + 128;
#pragma unroll
                for (int p = 0; p < 2; ++p) {
                    const int r = w * 16 + p * 8 + rsub;
                    g2l16(qkv + (rowbase + kb2 + r) * 3072 + 1024 + h * 64 + kchunk * 8,
                          SM + (c ? 0 : 8192) + w * 1024 + p * 512);
                    vreg[p] = *(const bf16x8*)(qkv + (rowbase + kb2 + r) * 3072 + 2048 + h * 64 + cstage * 8);
                }
            }

            if (kb <= qbase + 31) {   // strip visible
                bf16x8 kf[4][4];
#pragma unroll
                for (int kt = 0; kt < 4; ++kt)
#pragma unroll
                    for (int j = 0; j < 4; ++j)
                        kf[kt][j] = *(const bf16x8*)&Kb[((kt * 32 + lq) * 64 + j * 16 + lk * 8) ^ ((lq & 7) << 3)];

                f32x16 sf[4];
                __builtin_amdgcn_s_setprio(1);
#pragma unroll
                for (int kt = 0; kt < 4; ++kt) {
                    f32x16 z = (f32x16)(0.0f);
#pragma unroll
                    for (int j = 0; j < 4; ++j) z = MFMA32(kf[kt][j], qf[j], z, 0, 0, 0);
                    sf[kt] = z;
                }
                __builtin_amdgcn_s_setprio(0);

                float mt = -3e38f;
                if (kb + 127 > qbase) {         // diagonal region: causal mask
                    const int qrow = qbase + lq;
#pragma unroll
                    for (int kt = 0; kt < 4; ++kt)
#pragma unroll
                        for (int r = 0; r < 16; ++r) {
                            const int key = kb + kt * 32 + (r & 3) + 8 * (r >> 2) + 4 * lk;
                            float v = sf[kt][r];
                            if (key > qrow) v = -3e38f;
                            sf[kt][r] = v;
                            mt = fmaxf(mt, v);
                        }
                } else {
#pragma unroll
                    for (int kt = 0; kt < 4; ++kt)
#pragma unroll
                        for (int r = 0; r < 16; ++r) mt = fmaxf(mt, sf[kt][r]);
                }
                mt = red32_max(mt);

                const bool defer = __all(mt <= m_run + 16.0f);
                float mn = m_run;
                if (!defer) {
                    mn = fmaxf(m_run, mt);
                    const float alpha = EXP2F(m_run - mn);
                    m_run = mn;
                    l_run *= alpha;
#pragma unroll
                    for (int dt = 0; dt < 2; ++dt)
#pragma unroll
                        for (int r = 0; r < 16; ++r) ot[dt][r] *= alpha;
                }
                float rs = 0.0f;
#pragma unroll
                for (int kt = 0; kt < 4; ++kt)
#pragma unroll
                    for (int r = 0; r < 16; ++r) {
                        const float pp = EXP2F(sf[kt][r] - mn);
                        sf[kt][r] = pp;
                        rs += pp;
                    }
                l_run += red32_sum(rs);

                unsigned pc[4][4][2];
#pragma unroll
                for (int kt = 0; kt < 4; ++kt)
#pragma unroll
                    for (int rg = 0; rg < 4; ++rg) {
                        unsigned d0, d1;
                        asm("v_cvt_pk_bf16_f32 %0, %1, %2"
                            : "=v"(d0) : "v"((float)sf[kt][rg * 4 + 0]), "v"((float)sf[kt][rg * 4 + 1]));
                        asm("v_cvt_pk_bf16_f32 %0, %1, %2"
                            : "=v"(d1) : "v"((float)sf[kt][rg * 4 + 2]), "v"((float)sf[kt][rg * 4 + 3]));
                        pc[kt][rg][0] = d0;
                        pc[kt][rg][1] = d1;
                    }

                __builtin_amdgcn_s_setprio(1);
#pragma unroll
                for (int kt = 0; kt < 4; ++kt)
#pragma unroll
                    for (int hh = 0; hh < 2; ++hh) {
                        unsigned a0 = pc[kt][2 * hh][0], a1 = pc[kt][2 * hh][1];
                        unsigned b0 = pc[kt][2 * hh + 1][0], b1 = pc[kt][2 * hh + 1][1];
                        asm("v_permlane32_swap_b32 %0, %1" : "+v"(a0), "+v"(b0));
                        asm("v_permlane32_swap_b32 %0, %1" : "+v"(a1), "+v"(b1));
                        u32x4 wv = {a0, a1, b0, b1};
                        const bf16x8 pb = __builtin_bit_cast(bf16x8, wv);
                        const int k0 = 2 * kt + hh;
#pragma unroll
                        for (int dt = 0; dt < 2; ++dt) {
                            const int d = dt * 32 + lq;
                            const int vswz = ((d & 7) ^ (d >> 3)) & 7;
                            const bf16x8 vf = *(const bf16x8*)&Vb[((d * 128) + (k0 * 16 + lk * 8)) ^ (vswz << 3)];
                            ot[dt] = MFMA32(vf, pb, ot[dt], 0, 0, 0);
                        }
                    }
                __builtin_amdgcn_s_setprio(0);
            }

            asm volatile("s_waitcnt vmcnt(0)" ::: "memory");
            if (t + 1 < nt) {
                u16* const Vn = SM + 16384 + (c ? 0 : 8192);
#pragma unroll
                for (int p = 0; p < 2; ++p) {
                    const int r = w * 16 + p * 8 + rsub;
#pragma unroll
                    for (int i = 0; i < 8; ++i) {
                        const int d = cstage * 8 + i;
                        Vn[((d * 128 + r) ^ (((i ^ cstage) & 7) << 3))] = ((const u16*)&vreg[p])[i];
                    }
                }
            }
            __syncthreads();   // single barrier per tile-step
        }

        // ---- epilogue: O^T -> LDS transpose -> coalesced bf16 stores ----
        u16* const out_l = SM + w * 2176;   // [32][68] per wave (private region)
        const float inv = 1.0f / l_run;
#pragma unroll
        for (int dt = 0; dt < 2; ++dt)
#pragma unroll
            for (int r = 0; r < 16; ++r) {
                const int d = dt * 32 + (r & 3) + 8 * (r >> 2) + 4 * lk;
                out_l[lq * 68 + d] = f32_to_bf16_bits(ot[dt][r] * inv);
            }
#pragma unroll
        for (int rr = 0; rr < 4; ++rr) {
            const int row = rr * 8 + (l >> 3);
            const bf16x8 v = *(const bf16x8*)&out_l[row * 68 + (l & 7) * 8];
            *(bf16x8*)(ctx + (rowbase + qbase + row) * 1024 + h * 64 + (l & 7) * 8) = v;
        }
    }
}

extern "C" void kernel_launch(void* const* d_in, const int* in_sizes, int n_in,
                              void* d_out, int out_size, void* d_ws, size_t ws_size,
                              hipStream_t stream) {
    const float* x      = (const float*)d_in[0];
    const float* W_qkv  = (const float*)d_in[1];
    const float* b_qkv  = (const float*)d_in[2];
    const float* W_o    = (const float*)d_in[3];
    const float* b_o    = (const float*)d_in[4];
    float* out = (float*)d_out;

    const int M = 4 * 2048;     // 8192 rows
    const int C = 1024;
    u16* qkv   = (u16*)d_ws;                       // [8192][3072]
    u16* xb    = qkv   + (size_t)M * 3 * C;        // [8192][1024]
    u16* wqkvt = xb    + (size_t)M * C;            // [3072][1024]
    u16* ctx   = wqkvt + (size_t)3 * C * C;        // [8192][1024]
    u16* wot   = ctx   + (size_t)M * C;            // [1024][1024]

    const float SCQ = 0.125f * 1.44269504089f;     // 1/sqrt(64) * log2(e)

    cvt_bf16_kernel<<<(M * C) / (256 * 8), 256, 0, stream>>>(x, xb, M * C);
    cvt_t2_kernel<<<dim3(3 * C / 64 + C / 64, C / 32), 256, 0, stream>>>(
        W_qkv, wqkvt, 3 * C, W_o, wot, C, C);

    // QKV projection: v2 + L2-supertiled walk, grid 1536, nbx unused
    gemm_nt<1><<<(3 * C / 128) * (M / 128), 256, 0, stream>>>(xb, wqkvt, b_qkv, qkv,
                                                              M, 3 * C, C, C, SCQ, 3 * C / 128);

    attn_kernel<<<256, 512, 0, stream>>>(qkv, ctx);

    // output projection: v2 + supertiled walk (1 n-group), grid 512
    gemm_nt<0><<<(C / 128) * (M / 128), 256, 0, stream>>>(ctx, wot, b_o, out,
                                                          M, C, C, 0, 1.0f, C / 128);
}

// Round 22
// 161.931 us; speedup vs baseline: 1.0201x; 1.0021x over previous
//
#include <hip/hip_runtime.h>
#include <hip/hip_bf16.h>

typedef __attribute__((ext_vector_type(8))) __bf16 bf16x8;
typedef __attribute__((ext_vector_type(4))) float f32x4;
typedef __attribute__((ext_vector_type(16))) float f32x16;
typedef __attribute__((ext_vector_type(4))) unsigned short u16x4;
typedef __attribute__((ext_vector_type(8))) unsigned short u16x8;
typedef __attribute__((ext_vector_type(4))) unsigned int u32x4;
typedef unsigned short u16;

#define MFMA16 __builtin_amdgcn_mfma_f32_16x16x32_bf16
#define MFMA32 __builtin_amdgcn_mfma_f32_32x32x16_bf16

#if __has_builtin(__builtin_amdgcn_exp2f)
#define EXP2F __builtin_amdgcn_exp2f
#else
#define EXP2F(x) __expf((x) * 0.69314718056f)
#endif

__device__ inline u16 f32_to_bf16_bits(float f) {      // RNE (weights/outputs)
    unsigned u = __builtin_bit_cast(unsigned, f);
    unsigned r = u + 0x7FFFu + ((u >> 16) & 1u);
    return (u16)(r >> 16);
}

__device__ inline void g2l16(const void* g, void* l) {
    __builtin_amdgcn_global_load_lds(
        (const __attribute__((address_space(1))) unsigned int*)g,
        (__attribute__((address_space(3))) unsigned int*)l,
        16, 0, 0);
}

__device__ inline float red32_max(float x) { return fmaxf(x, __shfl_xor(x, 32)); }
__device__ inline float red32_sum(float x) { return x + __shfl_xor(x, 32); }

// ---------------- convert: f32 -> bf16, 8 elem/thread (16B stores) ----------------
__global__ void cvt_bf16_kernel(const float* __restrict__ in, u16* __restrict__ out, int n) {
    int i = (blockIdx.x * 256 + threadIdx.x) * 8;
    if (i >= n) return;
    f32x4 v0 = *(const f32x4*)&in[i];
    f32x4 v1 = *(const f32x4*)&in[i + 4];
    u16x8 r;
#pragma unroll
    for (int j = 0; j < 4; ++j) {
        r[j] = f32_to_bf16_bits(v0[j]);
        r[j + 4] = f32_to_bf16_bits(v1[j]);
    }
    *(u16x8*)&out[i] = r;
}

// ---------------- merged transpose+convert: both W matrices in one launch ----------------
__global__ __launch_bounds__(256) void cvt_t2_kernel(
    const float* __restrict__ W1, u16* __restrict__ WT1, int N1,
    const float* __restrict__ W2, u16* __restrict__ WT2, int N2, int K)
{
    int bx = blockIdx.x;
    const float* W; u16* WT; int N;
    const int nb1 = N1 >> 6;
    if (bx < nb1) { W = W1; WT = WT1; N = N1; }
    else          { W = W2; WT = WT2; N = N2; bx -= nb1; }
    const int w = threadIdx.x >> 6, l = threadIdx.x & 63;
    const int n = bx * 64 + l;
    const int k0 = blockIdx.y * 32 + w * 8;
    u16x8 r;
#pragma unroll
    for (int i = 0; i < 8; ++i)
        r[i] = f32_to_bf16_bits(W[(size_t)(k0 + i) * N + n]);
    *(u16x8*)&WT[(size_t)n * K + k0] = r;
}

// ---------------- GEMM v2 (proven) + L2-supertiled XCD walk, groups of 4 ----------------
// 128x128, BK=32, 3-deep counted vmcnt. Within each XCD: n-groups of 4
// n-tiles x 8 m-tiles (32 blocks/group) -> working set A 2MB + B 1MB = 3MB
// < 4MB L2, so the XCD's A-slice stays resident across ALL groups (fetched
// once; R21's groups-of-8 hit exactly 4MB and thrashed A 3x).
// Requires M/128 == 64 and (N/128) % 4 == 0 (3072/128=24 ok, 1024/128=8 ok).
template <int STORE_BF16>
__global__ __launch_bounds__(256) void gemm_nt(
    const u16* __restrict__ A, const u16* __restrict__ BT,
    const float* __restrict__ bias, void* __restrict__ Cv,
    int M, int N, int K, int qcols, float qscale, int nbx)
{
    __shared__ __align__(16) u16 SM[24576];   // 3 sets x (A[128][32] | B[128][32])
    const int tid = threadIdx.x;
    const int w = tid >> 6, l = tid & 63;
    const int lr = l & 15, lh = l >> 4;
    const int wr = (w >> 1) * 64, wc = (w & 1) * 64;

    // supertiled XCD-local mapping: xcd owns m-tiles [xcd*8, xcd*8+8);
    // within-xcd id j: group g = j>>5 picks 4 n-tiles; r = j&31 -> 8m x 4n.
    const int xcd = blockIdx.x & 7;
    const int j = blockIdx.x >> 3;
    const int g = j >> 5;
    const int r = j & 31;
    const int m0 = (xcd * 8 + (r >> 2)) * 128;
    const int n0 = (g * 4 + (r & 3)) * 128;
    (void)nbx;

    const int NT = K >> 5;

    const int f0 = tid, f1 = 256 + tid;
    const int r0 = f0 >> 2, r1 = f1 >> 2;
    const int cs0 = ((f0 & 3) ^ ((r0 >> 1) & 3)) * 8;
    const int cs1 = ((f1 & 3) ^ ((r1 >> 1) & 3)) * 8;
    const size_t arow0 = (size_t)(m0 + r0) * K, arow1 = (size_t)(m0 + r1) * K;
    const size_t brow0 = (size_t)(n0 + r0) * K, brow1 = (size_t)(n0 + r1) * K;

#define STAGE_TILE(t, set)                                                     \
    do {                                                                       \
        const int kk_ = (t) * 32;                                              \
        u16* dst_ = SM + (set) * 8192 + w * 512;                               \
        g2l16(A + arow0 + kk_ + cs0, dst_);                                    \
        g2l16(BT + brow0 + kk_ + cs0, dst_ + 4096);                            \
        g2l16(A + arow1 + kk_ + cs1, dst_ + 2048);                             \
        g2l16(BT + brow1 + kk_ + cs1, dst_ + 4096 + 2048);                     \
    } while (0)

    f32x4 acc[4][4];
#pragma unroll
    for (int m = 0; m < 4; ++m)
#pragma unroll
        for (int n = 0; n < 4; ++n) acc[m][n] = (f32x4)(0.0f);

    STAGE_TILE(0, 0);
    STAGE_TILE(1, 1);
    asm volatile("s_waitcnt vmcnt(4) lgkmcnt(0)\n\ts_barrier" ::: "memory");

    const int csw = (lr >> 1) & 3;
    int s0 = 0, s2 = 2;
    for (int t = 0; t < NT; ++t) {
        if (t + 2 < NT) STAGE_TILE(t + 2, s2);

        const u16* As = SM + s0 * 8192;
        const u16* Bs = As + 4096;
        bf16x8 af[4], bfr[4];
#pragma unroll
        for (int m = 0; m < 4; ++m)
            af[m] = *(const bf16x8*)&As[(wr + m * 16 + lr) * 32 + ((lh ^ csw) << 3)];
#pragma unroll
        for (int n = 0; n < 4; ++n)
            bfr[n] = *(const bf16x8*)&Bs[(wc + n * 16 + lr) * 32 + ((lh ^ csw) << 3)];
        __builtin_amdgcn_s_setprio(1);
#pragma unroll
        for (int m = 0; m < 4; ++m)
#pragma unroll
            for (int n = 0; n < 4; ++n)
                acc[m][n] = MFMA16(af[m], bfr[n], acc[m][n], 0, 0, 0);
        __builtin_amdgcn_s_setprio(0);

        if (t + 2 < NT)
            asm volatile("s_waitcnt vmcnt(4) lgkmcnt(0)\n\ts_barrier" ::: "memory");
        else if (t + 1 < NT)
            asm volatile("s_waitcnt vmcnt(0) lgkmcnt(0)\n\ts_barrier" ::: "memory");

        s0 = (s0 == 2) ? 0 : s0 + 1;
        s2 = (s2 == 2) ? 0 : s2 + 1;
    }
#undef STAGE_TILE

#pragma unroll
    for (int m = 0; m < 4; ++m) {
        int row = m0 + wr + m * 16 + lh * 4;
#pragma unroll
        for (int n = 0; n < 4; ++n) {
            int col = n0 + wc + n * 16 + lr;
            float bs = bias[col];
            float sc = (col < qcols) ? qscale : 1.0f;
#pragma unroll
            for (int j2 = 0; j2 < 4; ++j2) {
                float v = (acc[m][n][j2] + bs) * sc;
                if (STORE_BF16)
                    ((u16*)Cv)[(size_t)(row + j2) * N + col] = f32_to_bf16_bits(v);
                else
                    ((float*)Cv)[(size_t)(row + j2) * N + col] = v;
            }
        }
    }
}

// ---------------- causal flash attention v9 (proven R15): KVBLK=128 ----------------
__global__ __launch_bounds__(512, 1) void attn_kernel(
    const u16* __restrict__ qkv, u16* __restrict__ ctx)
{
    __shared__ __align__(16) u16 SM[32768];  // K 2x8K u16 | V 2x8K u16

    const int bid = blockIdx.x;
    const int xcd = bid & 7, jj = bid >> 3;        // 32 blocks per XCD
    const int bh = xcd * 8 + (jj >> 2);            // 8 heads per XCD (4MB KV = L2)
    const int pr = jj & 3;                         // pair: qt = pr, then 7-pr
    const int b = bh >> 4, h = bh & 15;
    const size_t rowbase = (size_t)b * 2048;
    const int tid = threadIdx.x, w = tid >> 6, l = tid & 63;
    const int lq = l & 31, lk = l >> 5;            // q-col owner, k-half

    const int rsub = l >> 3;                       // row within 8-row group
    const int cstage = l & 7;
    const int kchunk = cstage ^ rsub;              // inverse-swizzle src (key=row&7)

    bf16x8 vreg[2];

#pragma unroll
    for (int pass = 0; pass < 2; ++pass) {
        const int qt = pass ? (7 - pr) : pr;
        const int q0 = qt * 256;
        const int nt = 2 * qt + 2;                 // 128-wide K/V tiles
        const int qbase = q0 + w * 32;

        const u16* qp = qkv + (rowbase + qbase + lq) * 3072 + h * 64 + lk * 8;
        bf16x8 qf[4];
#pragma unroll
        for (int j = 0; j < 4; ++j) qf[j] = *(const bf16x8*)(qp + j * 16);

        f32x16 ot[2];
#pragma unroll
        for (int dt = 0; dt < 2; ++dt) ot[dt] = (f32x16)(0.0f);
        float m_run = -3e38f, l_run = 0.0f;

        // ---- prologue: stage tile 0 ----
        __syncthreads();
#pragma unroll
        for (int p = 0; p < 2; ++p) {
            const int r = w * 16 + p * 8 + rsub;
            g2l16(qkv + (rowbase + r) * 3072 + 1024 + h * 64 + kchunk * 8,
                  SM + w * 1024 + p * 512);
            vreg[p] = *(const bf16x8*)(qkv + (rowbase + r) * 3072 + 2048 + h * 64 + cstage * 8);
        }
        asm volatile("s_waitcnt vmcnt(0)" ::: "memory");
#pragma unroll
        for (int p = 0; p < 2; ++p) {
            const int r = w * 16 + p * 8 + rsub;
#pragma unroll
            for (int i = 0; i < 8; ++i) {
                const int d = cstage * 8 + i;
                SM[16384 + ((d * 128 + r) ^ (((i ^ cstage) & 7) << 3))] = ((const u16*)&vreg[p])[i];
            }
        }
        __syncthreads();

        for (int t = 0; t < nt; ++t) {
            const int c = t & 1;
            const int kb = t * 128;
            u16* const Kb = SM + (c ? 8192 : 0);
            u16* const Vb = SM + 16384 + (c ? 8192 : 0);

            if (t + 1 < nt) {   // issue next-tile staging first
                const int kb2 = kb + 128;
#pragma unroll
                for (int p = 0; p < 2; ++p) {
                    const int r = w * 16 + p * 8 + rsub;
                    g2l16(qkv + (rowbase + kb2 + r) * 3072 + 1024 + h * 64 + kchunk * 8,
                          SM + (c ? 0 : 8192) + w * 1024 + p * 512);
                    vreg[p] = *(const bf16x8*)(qkv + (rowbase + kb2 + r) * 3072 + 2048 + h * 64 + cstage * 8);
                }
            }

            if (kb <= qbase + 31) {   // strip visible
                bf16x8 kf[4][4];
#pragma unroll
                for (int kt = 0; kt < 4; ++kt)
#pragma unroll
                    for (int j = 0; j < 4; ++j)
                        kf[kt][j] = *(const bf16x8*)&Kb[((kt * 32 + lq) * 64 + j * 16 + lk * 8) ^ ((lq & 7) << 3)];

                f32x16 sf[4];
                __builtin_amdgcn_s_setprio(1);
#pragma unroll
                for (int kt = 0; kt < 4; ++kt) {
                    f32x16 z = (f32x16)(0.0f);
#pragma unroll
                    for (int j = 0; j < 4; ++j) z = MFMA32(kf[kt][j], qf[j], z, 0, 0, 0);
                    sf[kt] = z;
                }
                __builtin_amdgcn_s_setprio(0);

                float mt = -3e38f;
                if (kb + 127 > qbase) {         // diagonal region: causal mask
                    const int qrow = qbase + lq;
#pragma unroll
                    for (int kt = 0; kt < 4; ++kt)
#pragma unroll
                        for (int r = 0; r < 16; ++r) {
                            const int key = kb + kt * 32 + (r & 3) + 8 * (r >> 2) + 4 * lk;
                            float v = sf[kt][r];
                            if (key > qrow) v = -3e38f;
                            sf[kt][r] = v;
                            mt = fmaxf(mt, v);
                        }
                } else {
#pragma unroll
                    for (int kt = 0; kt < 4; ++kt)
#pragma unroll
                        for (int r = 0; r < 16; ++r) mt = fmaxf(mt, sf[kt][r]);
                }
                mt = red32_max(mt);

                const bool defer = __all(mt <= m_run + 16.0f);
                float mn = m_run;
                if (!defer) {
                    mn = fmaxf(m_run, mt);
                    const float alpha = EXP2F(m_run - mn);
                    m_run = mn;
                    l_run *= alpha;
#pragma unroll
                    for (int dt = 0; dt < 2; ++dt)
#pragma unroll
                        for (int r = 0; r < 16; ++r) ot[dt][r] *= alpha;
                }
                float rs = 0.0f;
#pragma unroll
                for (int kt = 0; kt < 4; ++kt)
#pragma unroll
                    for (int r = 0; r < 16; ++r) {
                        const float pp = EXP2F(sf[kt][r] - mn);
                        sf[kt][r] = pp;
                        rs += pp;
                    }
                l_run += red32_sum(rs);

                unsigned pc[4][4][2];
#pragma unroll
                for (int kt = 0; kt < 4; ++kt)
#pragma unroll
                    for (int rg = 0; rg < 4; ++rg) {
                        unsigned d0, d1;
                        asm("v_cvt_pk_bf16_f32 %0, %1, %2"
                            : "=v"(d0) : "v"((float)sf[kt][rg * 4 + 0]), "v"((float)sf[kt][rg * 4 + 1]));
                        asm("v_cvt_pk_bf16_f32 %0, %1, %2"
                            : "=v"(d1) : "v"((float)sf[kt][rg * 4 + 2]), "v"((float)sf[kt][rg * 4 + 3]));
                        pc[kt][rg][0] = d0;
                        pc[kt][rg][1] = d1;
                    }

                __builtin_amdgcn_s_setprio(1);
#pragma unroll
                for (int kt = 0; kt < 4; ++kt)
#pragma unroll
                    for (int hh = 0; hh < 2; ++hh) {
                        unsigned a0 = pc[kt][2 * hh][0], a1 = pc[kt][2 * hh][1];
                        unsigned b0 = pc[kt][2 * hh + 1][0], b1 = pc[kt][2 * hh + 1][1];
                        asm("v_permlane32_swap_b32 %0, %1" : "+v"(a0), "+v"(b0));
                        asm("v_permlane32_swap_b32 %0, %1" : "+v"(a1), "+v"(b1));
                        u32x4 wv = {a0, a1, b0, b1};
                        const bf16x8 pb = __builtin_bit_cast(bf16x8, wv);
                        const int k0 = 2 * kt + hh;
#pragma unroll
                        for (int dt = 0; dt < 2; ++dt) {
                            const int d = dt * 32 + lq;
                            const int vswz = ((d & 7) ^ (d >> 3)) & 7;
                            const bf16x8 vf = *(const bf16x8*)&Vb[((d * 128) + (k0 * 16 + lk * 8)) ^ (vswz << 3)];
                            ot[dt] = MFMA32(vf, pb, ot[dt], 0, 0, 0);
                        }
                    }
                __builtin_amdgcn_s_setprio(0);
            }

            asm volatile("s_waitcnt vmcnt(0)" ::: "memory");
            if (t + 1 < nt) {
                u16* const Vn = SM + 16384 + (c ? 0 : 8192);
#pragma unroll
                for (int p = 0; p < 2; ++p) {
                    const int r = w * 16 + p * 8 + rsub;
#pragma unroll
                    for (int i = 0; i < 8; ++i) {
                        const int d = cstage * 8 + i;
                        Vn[((d * 128 + r) ^ (((i ^ cstage) & 7) << 3))] = ((const u16*)&vreg[p])[i];
                    }
                }
            }
            __syncthreads();   // single barrier per tile-step
        }

        // ---- epilogue: O^T -> LDS transpose -> coalesced bf16 stores ----
        u16* const out_l = SM + w * 2176;   // [32][68] per wave (private region)
        const float inv = 1.0f / l_run;
#pragma unroll
        for (int dt = 0; dt < 2; ++dt)
#pragma unroll
            for (int r = 0; r < 16; ++r) {
                const int d = dt * 32 + (r & 3) + 8 * (r >> 2) + 4 * lk;
                out_l[lq * 68 + d] = f32_to_bf16_bits(ot[dt][r] * inv);
            }
#pragma unroll
        for (int rr = 0; rr < 4; ++rr) {
            const int row = rr * 8 + (l >> 3);
            const bf16x8 v = *(const bf16x8*)&out_l[row * 68 + (l & 7) * 8];
            *(bf16x8*)(ctx + (rowbase + qbase + row) * 1024 + h * 64 + (l & 7) * 8) = v;
        }
    }
}

extern "C" void kernel_launch(void* const* d_in, const int* in_sizes, int n_in,
                              void* d_out, int out_size, void* d_ws, size_t ws_size,
                              hipStream_t stream) {
    const float* x      = (const float*)d_in[0];
    const float* W_qkv  = (const float*)d_in[1];
    const float* b_qkv  = (const float*)d_in[2];
    const float* W_o    = (const float*)d_in[3];
    const float* b_o    = (const float*)d_in[4];
    float* out = (float*)d_out;

    const int M = 4 * 2048;     // 8192 rows
    const int C = 1024;
    u16* qkv   = (u16*)d_ws;                       // [8192][3072]
    u16* xb    = qkv   + (size_t)M * 3 * C;        // [8192][1024]
    u16* wqkvt = xb    + (size_t)M * C;            // [3072][1024]
    u16* ctx   = wqkvt + (size_t)3 * C * C;        // [8192][1024]
    u16* wot   = ctx   + (size_t)M * C;            // [1024][1024]

    const float SCQ = 0.125f * 1.44269504089f;     // 1/sqrt(64) * log2(e)

    cvt_bf16_kernel<<<(M * C) / (256 * 8), 256, 0, stream>>>(x, xb, M * C);
    cvt_t2_kernel<<<dim3(3 * C / 64 + C / 64, C / 32), 256, 0, stream>>>(
        W_qkv, wqkvt, 3 * C, W_o, wot, C, C);

    // QKV projection: v2 + L2-supertiled walk (groups of 4), grid 1536
    gemm_nt<1><<<(3 * C / 128) * (M / 128), 256, 0, stream>>>(xb, wqkvt, b_qkv, qkv,
                                                              M, 3 * C, C, C, SCQ, 3 * C / 128);

    attn_kernel<<<256, 512, 0, stream>>>(qkv, ctx);

    // output projection: v2 + supertiled walk (2 n-groups), grid 512
    gemm_nt<0><<<(C / 128) * (M / 128), 256, 0, stream>>>(ctx, wot, b_o, out,
                                                          M, C, C, 0, 1.0f, C / 128);
}

// Round 23
// 160.702 us; speedup vs baseline: 1.0279x; 1.0076x over previous
//
#include <hip/hip_runtime.h>
#include <hip/hip_bf16.h>

typedef __attribute__((ext_vector_type(8))) __bf16 bf16x8;
typedef __attribute__((ext_vector_type(4))) float f32x4;
typedef __attribute__((ext_vector_type(16))) float f32x16;
typedef __attribute__((ext_vector_type(4))) unsigned short u16x4;
typedef __attribute__((ext_vector_type(8))) unsigned short u16x8;
typedef __attribute__((ext_vector_type(4))) unsigned int u32x4;
typedef unsigned short u16;

#define MFMA16 __builtin_amdgcn_mfma_f32_16x16x32_bf16
#define MFMA32 __builtin_amdgcn_mfma_f32_32x32x16_bf16

#if __has_builtin(__builtin_amdgcn_exp2f)
#define EXP2F __builtin_amdgcn_exp2f
#else
#define EXP2F(x) __expf((x) * 0.69314718056f)
#endif

__device__ inline u16 f32_to_bf16_bits(float f) {      // RNE (weights/outputs)
    unsigned u = __builtin_bit_cast(unsigned, f);
    unsigned r = u + 0x7FFFu + ((u >> 16) & 1u);
    return (u16)(r >> 16);
}

__device__ inline void g2l16(const void* g, void* l) {
    __builtin_amdgcn_global_load_lds(
        (const __attribute__((address_space(1))) unsigned int*)g,
        (__attribute__((address_space(3))) unsigned int*)l,
        16, 0, 0);
}

__device__ inline float red32_max(float x) { return fmaxf(x, __shfl_xor(x, 32)); }
__device__ inline float red32_sum(float x) { return x + __shfl_xor(x, 32); }

// ---------------- convert: f32 -> bf16, 8 elem/thread (16B stores) ----------------
__global__ void cvt_bf16_kernel(const float* __restrict__ in, u16* __restrict__ out, int n) {
    int i = (blockIdx.x * 256 + threadIdx.x) * 8;
    if (i >= n) return;
    f32x4 v0 = *(const f32x4*)&in[i];
    f32x4 v1 = *(const f32x4*)&in[i + 4];
    u16x8 r;
#pragma unroll
    for (int j = 0; j < 4; ++j) {
        r[j] = f32_to_bf16_bits(v0[j]);
        r[j + 4] = f32_to_bf16_bits(v1[j]);
    }
    *(u16x8*)&out[i] = r;
}

// ---------------- merged transpose+convert: both W matrices in one launch ----------------
__global__ __launch_bounds__(256) void cvt_t2_kernel(
    const float* __restrict__ W1, u16* __restrict__ WT1, int N1,
    const float* __restrict__ W2, u16* __restrict__ WT2, int N2, int K)
{
    int bx = blockIdx.x;
    const float* W; u16* WT; int N;
    const int nb1 = N1 >> 6;
    if (bx < nb1) { W = W1; WT = WT1; N = N1; }
    else          { W = W2; WT = WT2; N = N2; bx -= nb1; }
    const int w = threadIdx.x >> 6, l = threadIdx.x & 63;
    const int n = bx * 64 + l;
    const int k0 = blockIdx.y * 32 + w * 8;
    u16x8 r;
#pragma unroll
    for (int i = 0; i < 8; ++i)
        r[i] = f32_to_bf16_bits(W[(size_t)(k0 + i) * N + n]);
    *(u16x8*)&WT[(size_t)n * K + k0] = r;
}

// ---------------- GEMM 8p2: 128x256 tile, BK=64, 8 waves, 2 phases/K-tile ----------------
// R17's verified phase schedule with (a) tail-free grid: 768 blocks = 3.0
// rounds at 1 block/CU (96KB LDS); (b) A-frags read once per K-tile and HELD
// in VGPRs across phases (16 ds_read per 32 MFMA, was 48/64). Counted
// vmcnt(2) gate (chunk0 of j+1 in flight), never drains mid-loop. Supertiled
// XCD walk: xcd owns 8 m-tiles; groups of 8m x 2n -> A 2MB + B 1MB = 3MB < L2.
template <int STORE_BF16>
__global__ __launch_bounds__(512) void gemm_8p2(
    const u16* __restrict__ A, const u16* __restrict__ BT,
    const float* __restrict__ bias, void* __restrict__ Cv,
    int M, int N, int K, int qcols, float qscale)
{
    __shared__ __align__(16) u16 SM[49152];   // 2 bufs x (A[128][64] | B[256][64])
    const int tid = threadIdx.x;
    const int w = tid >> 6, l = tid & 63;
    const int lr = l & 15, lh = l >> 4;
    const int wr = (w >> 2) * 64;             // 2 wave-rows
    const int wc = (w & 3) * 64;              // 4 wave-cols

    // supertiled XCD-local mapping: 768 blocks = 8 xcd x (6 groups x 8m x 2n)
    const int xcd = blockIdx.x & 7;
    const int jb = blockIdx.x >> 3;           // 0..95
    const int g = jb >> 4;                    // 0..5 (n-groups of 2)
    const int r = jb & 15;
    const int m0 = (xcd * 8 + (r >> 1)) * 128;
    const int n0 = (g * 2 + (r & 1)) * 256;

    const int NT = K >> 6;                    // BK=64

    // staging: 3 chunks/K-tile (A 128 rows, B rows 0-127, B rows 128-255);
    // each chunk = 1024 g2l16 = 2/thread. flat f: row f>>3, dest chunk f&7,
    // global source chunk pre-swizzled with key row&7 (both-sides, G21).
    const int f0 = tid, f1 = 512 + tid;
    const int r0 = f0 >> 3, r1 = f1 >> 3;     // r1 = r0 + 64
    const int c0 = ((f0 & 7) ^ (r0 & 7)) * 8; // (r1&7)==(r0&7) -> same key

#define STAGE_CHUNK(j, c)                                                       \
    do {                                                                        \
        const int kk_ = (j) * 64;                                               \
        u16* db_ = SM + (((j) & 1) * 24576) + (c) * 8192;                       \
        const u16* base_ = ((c) == 0) ? (A + (size_t)m0 * K)                    \
                                      : (BT + (size_t)(n0 + ((c)-1) * 128) * K);\
        g2l16(base_ + (size_t)r0 * K + kk_ + c0, db_ + f0 * 8);                 \
        g2l16(base_ + (size_t)r1 * K + kk_ + c0, db_ + f1 * 8);                 \
    } while (0)

    f32x4 acc[4][4];
#pragma unroll
    for (int m = 0; m < 4; ++m)
#pragma unroll
        for (int n = 0; n < 4; ++n) acc[m][n] = (f32x4)(0.0f);

    // prologue: tile 0 fully in flight (6 loads)
    STAGE_CHUNK(0, 0); STAGE_CHUNK(0, 1); STAGE_CHUNK(0, 2);

    const int swk = lr & 7;                   // ds_read swizzle key (= row&7)
    for (int j = 0; j < NT; ++j) {
        const u16* Ab = SM + (j & 1) * 24576;
        const u16* Bb = Ab + 8192;

        // ---- phase 0: gate + A(held) + B frags 0,1 ----
        if (j + 1 < NT) {
            STAGE_CHUNK(j + 1, 0);
            asm volatile("s_waitcnt vmcnt(2)\n\ts_barrier" ::: "memory");
        } else {
            asm volatile("s_waitcnt vmcnt(0)\n\ts_barrier" ::: "memory");
        }

        bf16x8 af[4][2], bfr[2][2];
#pragma unroll
        for (int m = 0; m < 4; ++m) {
            const int row = wr + m * 16 + lr;
#pragma unroll
            for (int ks = 0; ks < 2; ++ks)
                af[m][ks] = *(const bf16x8*)&Ab[row * 64 + (((ks * 4 + lh) ^ swk) << 3)];
        }
#pragma unroll
        for (int n = 0; n < 2; ++n) {
            const int row = wc + n * 16 + lr;
#pragma unroll
            for (int ks = 0; ks < 2; ++ks)
                bfr[n][ks] = *(const bf16x8*)&Bb[row * 64 + (((ks * 4 + lh) ^ swk) << 3)];
        }
        if (j + 1 < NT) STAGE_CHUNK(j + 1, 1);

        asm volatile("s_barrier\n\ts_waitcnt lgkmcnt(0)" ::: "memory");
        __builtin_amdgcn_s_setprio(1);
#pragma unroll
        for (int m = 0; m < 4; ++m)
#pragma unroll
            for (int n = 0; n < 2; ++n)
#pragma unroll
                for (int ks = 0; ks < 2; ++ks)
                    acc[m][n] = MFMA16(af[m][ks], bfr[n][ks], acc[m][n], 0, 0, 0);
        __builtin_amdgcn_s_setprio(0);
        asm volatile("s_barrier" ::: "memory");

        // ---- phase 1: B frags 2,3 (A held in VGPRs) ----
#pragma unroll
        for (int n = 0; n < 2; ++n) {
            const int row = wc + (n + 2) * 16 + lr;
#pragma unroll
            for (int ks = 0; ks < 2; ++ks)
                bfr[n][ks] = *(const bf16x8*)&Bb[row * 64 + (((ks * 4 + lh) ^ swk) << 3)];
        }
        if (j + 1 < NT) STAGE_CHUNK(j + 1, 2);

        asm volatile("s_barrier\n\ts_waitcnt lgkmcnt(0)" ::: "memory");
        __builtin_amdgcn_s_setprio(1);
#pragma unroll
        for (int m = 0; m < 4; ++m)
#pragma unroll
            for (int n = 0; n < 2; ++n)
#pragma unroll
                for (int ks = 0; ks < 2; ++ks)
                    acc[m][n + 2] = MFMA16(af[m][ks], bfr[n][ks], acc[m][n + 2], 0, 0, 0);
        __builtin_amdgcn_s_setprio(0);
        asm volatile("s_barrier" ::: "memory");
    }
#undef STAGE_CHUNK

#pragma unroll
    for (int m = 0; m < 4; ++m) {
        int row = m0 + wr + m * 16 + lh * 4;
#pragma unroll
        for (int n = 0; n < 4; ++n) {
            int col = n0 + wc + n * 16 + lr;
            float bs = bias[col];
            float sc = (col < qcols) ? qscale : 1.0f;
#pragma unroll
            for (int j2 = 0; j2 < 4; ++j2) {
                float v = (acc[m][n][j2] + bs) * sc;
                if (STORE_BF16)
                    ((u16*)Cv)[(size_t)(row + j2) * N + col] = f32_to_bf16_bits(v);
                else
                    ((float*)Cv)[(size_t)(row + j2) * N + col] = v;
            }
        }
    }
}

// ---------------- GEMM v2 (proven) + supertiled walk (groups of 4) -- out-proj ----------------
template <int STORE_BF16>
__global__ __launch_bounds__(256) void gemm_nt(
    const u16* __restrict__ A, const u16* __restrict__ BT,
    const float* __restrict__ bias, void* __restrict__ Cv,
    int M, int N, int K, int qcols, float qscale, int nbx)
{
    __shared__ __align__(16) u16 SM[24576];   // 3 sets x (A[128][32] | B[128][32])
    const int tid = threadIdx.x;
    const int w = tid >> 6, l = tid & 63;
    const int lr = l & 15, lh = l >> 4;
    const int wr = (w >> 1) * 64, wc = (w & 1) * 64;

    const int xcd = blockIdx.x & 7;
    const int j = blockIdx.x >> 3;
    const int g = j >> 5;
    const int r = j & 31;
    const int m0 = (xcd * 8 + (r >> 2)) * 128;
    const int n0 = (g * 4 + (r & 3)) * 128;
    (void)nbx;

    const int NT = K >> 5;

    const int f0 = tid, f1 = 256 + tid;
    const int r0 = f0 >> 2, r1 = f1 >> 2;
    const int cs0 = ((f0 & 3) ^ ((r0 >> 1) & 3)) * 8;
    const int cs1 = ((f1 & 3) ^ ((r1 >> 1) & 3)) * 8;
    const size_t arow0 = (size_t)(m0 + r0) * K, arow1 = (size_t)(m0 + r1) * K;
    const size_t brow0 = (size_t)(n0 + r0) * K, brow1 = (size_t)(n0 + r1) * K;

#define STAGE_TILE(t, set)                                                     \
    do {                                                                       \
        const int kk_ = (t) * 32;                                              \
        u16* dst_ = SM + (set) * 8192 + w * 512;                               \
        g2l16(A + arow0 + kk_ + cs0, dst_);                                    \
        g2l16(BT + brow0 + kk_ + cs0, dst_ + 4096);                            \
        g2l16(A + arow1 + kk_ + cs1, dst_ + 2048);                             \
        g2l16(BT + brow1 + kk_ + cs1, dst_ + 4096 + 2048);                     \
    } while (0)

    f32x4 acc[4][4];
#pragma unroll
    for (int m = 0; m < 4; ++m)
#pragma unroll
        for (int n = 0; n < 4; ++n) acc[m][n] = (f32x4)(0.0f);

    STAGE_TILE(0, 0);
    STAGE_TILE(1, 1);
    asm volatile("s_waitcnt vmcnt(4) lgkmcnt(0)\n\ts_barrier" ::: "memory");

    const int csw = (lr >> 1) & 3;
    int s0 = 0, s2 = 2;
    for (int t = 0; t < NT; ++t) {
        if (t + 2 < NT) STAGE_TILE(t + 2, s2);

        const u16* As = SM + s0 * 8192;
        const u16* Bs = As + 4096;
        bf16x8 af[4], bfr[4];
#pragma unroll
        for (int m = 0; m < 4; ++m)
            af[m] = *(const bf16x8*)&As[(wr + m * 16 + lr) * 32 + ((lh ^ csw) << 3)];
#pragma unroll
        for (int n = 0; n < 4; ++n)
            bfr[n] = *(const bf16x8*)&Bs[(wc + n * 16 + lr) * 32 + ((lh ^ csw) << 3)];
        __builtin_amdgcn_s_setprio(1);
#pragma unroll
        for (int m = 0; m < 4; ++m)
#pragma unroll
            for (int n = 0; n < 4; ++n)
                acc[m][n] = MFMA16(af[m], bfr[n], acc[m][n], 0, 0, 0);
        __builtin_amdgcn_s_setprio(0);

        if (t + 2 < NT)
            asm volatile("s_waitcnt vmcnt(4) lgkmcnt(0)\n\ts_barrier" ::: "memory");
        else if (t + 1 < NT)
            asm volatile("s_waitcnt vmcnt(0) lgkmcnt(0)\n\ts_barrier" ::: "memory");

        s0 = (s0 == 2) ? 0 : s0 + 1;
        s2 = (s2 == 2) ? 0 : s2 + 1;
    }
#undef STAGE_TILE

#pragma unroll
    for (int m = 0; m < 4; ++m) {
        int row = m0 + wr + m * 16 + lh * 4;
#pragma unroll
        for (int n = 0; n < 4; ++n) {
            int col = n0 + wc + n * 16 + lr;
            float bs = bias[col];
            float sc = (col < qcols) ? qscale : 1.0f;
#pragma unroll
            for (int j2 = 0; j2 < 4; ++j2) {
                float v = (acc[m][n][j2] + bs) * sc;
                if (STORE_BF16)
                    ((u16*)Cv)[(size_t)(row + j2) * N + col] = f32_to_bf16_bits(v);
                else
                    ((float*)Cv)[(size_t)(row + j2) * N + col] = v;
            }
        }
    }
}

// ---------------- causal flash attention v9 (proven R15): KVBLK=128 ----------------
__global__ __launch_bounds__(512, 1) void attn_kernel(
    const u16* __restrict__ qkv, u16* __restrict__ ctx)
{
    __shared__ __align__(16) u16 SM[32768];  // K 2x8K u16 | V 2x8K u16

    const int bid = blockIdx.x;
    const int xcd = bid & 7, jj = bid >> 3;        // 32 blocks per XCD
    const int bh = xcd * 8 + (jj >> 2);            // 8 heads per XCD (4MB KV = L2)
    const int pr = jj & 3;                         // pair: qt = pr, then 7-pr
    const int b = bh >> 4, h = bh & 15;
    const size_t rowbase = (size_t)b * 2048;
    const int tid = threadIdx.x, w = tid >> 6, l = tid & 63;
    const int lq = l & 31, lk = l >> 5;            // q-col owner, k-half

    const int rsub = l >> 3;                       // row within 8-row group
    const int cstage = l & 7;
    const int kchunk = cstage ^ rsub;              // inverse-swizzle src (key=row&7)

    bf16x8 vreg[2];

#pragma unroll
    for (int pass = 0; pass < 2; ++pass) {
        const int qt = pass ? (7 - pr) : pr;
        const int q0 = qt * 256;
        const int nt = 2 * qt + 2;                 // 128-wide K/V tiles
        const int qbase = q0 + w * 32;

        const u16* qp = qkv + (rowbase + qbase + lq) * 3072 + h * 64 + lk * 8;
        bf16x8 qf[4];
#pragma unroll
        for (int j = 0; j < 4; ++j) qf[j] = *(const bf16x8*)(qp + j * 16);

        f32x16 ot[2];
#pragma unroll
        for (int dt = 0; dt < 2; ++dt) ot[dt] = (f32x16)(0.0f);
        float m_run = -3e38f, l_run = 0.0f;

        // ---- prologue: stage tile 0 ----
        __syncthreads();
#pragma unroll
        for (int p = 0; p < 2; ++p) {
            const int r = w * 16 + p * 8 + rsub;
            g2l16(qkv + (rowbase + r) * 3072 + 1024 + h * 64 + kchunk * 8,
                  SM + w * 1024 + p * 512);
            vreg[p] = *(const bf16x8*)(qkv + (rowbase + r) * 3072 + 2048 + h * 64 + cstage * 8);
        }
        asm volatile("s_waitcnt vmcnt(0)" ::: "memory");
#pragma unroll
        for (int p = 0; p < 2; ++p) {
            const int r = w * 16 + p * 8 + rsub;
#pragma unroll
            for (int i = 0; i < 8; ++i) {
                const int d = cstage * 8 + i;
                SM[16384 + ((d * 128 + r) ^ (((i ^ cstage) & 7) << 3))] = ((const u16*)&vreg[p])[i];
            }
        }
        __syncthreads();

        for (int t = 0; t < nt; ++t) {
            const int c = t & 1;
            const int kb = t * 128;
            u16* const Kb = SM + (c ? 8192 : 0);
            u16* const Vb = SM + 16384 + (c ? 8192 : 0);

            if (t + 1 < nt) {   // issue next-tile staging first
                const int kb2 = kb + 128;
#pragma unroll
                for (int p = 0; p < 2; ++p) {
                    const int r = w * 16 + p * 8 + rsub;
                    g2l16(qkv + (rowbase + kb2 + r) * 3072 + 1024 + h * 64 + kchunk * 8,
                          SM + (c ? 0 : 8192) + w * 1024 + p * 512);
                    vreg[p] = *(const bf16x8*)(qkv + (rowbase + kb2 + r) * 3072 + 2048 + h * 64 + cstage * 8);
                }
            }

            if (kb <= qbase + 31) {   // strip visible
                bf16x8 kf[4][4];
#pragma unroll
                for (int kt = 0; kt < 4; ++kt)
#pragma unroll
                    for (int j = 0; j < 4; ++j)
                        kf[kt][j] = *(const bf16x8*)&Kb[((kt * 32 + lq) * 64 + j * 16 + lk * 8) ^ ((lq & 7) << 3)];

                f32x16 sf[4];
                __builtin_amdgcn_s_setprio(1);
#pragma unroll
                for (int kt = 0; kt < 4; ++kt) {
                    f32x16 z = (f32x16)(0.0f);
#pragma unroll
                    for (int j = 0; j < 4; ++j) z = MFMA32(kf[kt][j], qf[j], z, 0, 0, 0);
                    sf[kt] = z;
                }
                __builtin_amdgcn_s_setprio(0);

                float mt = -3e38f;
                if (kb + 127 > qbase) {         // diagonal region: causal mask
                    const int qrow = qbase + lq;
#pragma unroll
                    for (int kt = 0; kt < 4; ++kt)
#pragma unroll
                        for (int r = 0; r < 16; ++r) {
                            const int key = kb + kt * 32 + (r & 3) + 8 * (r >> 2) + 4 * lk;
                            float v = sf[kt][r];
                            if (key > qrow) v = -3e38f;
                            sf[kt][r] = v;
                            mt = fmaxf(mt, v);
                        }
                } else {
#pragma unroll
                    for (int kt = 0; kt < 4; ++kt)
#pragma unroll
                        for (int r = 0; r < 16; ++r) mt = fmaxf(mt, sf[kt][r]);
                }
                mt = red32_max(mt);

                const bool defer = __all(mt <= m_run + 16.0f);
                float mn = m_run;
                if (!defer) {
                    mn = fmaxf(m_run, mt);
                    const float alpha = EXP2F(m_run - mn);
                    m_run = mn;
                    l_run *= alpha;
#pragma unroll
                    for (int dt = 0; dt < 2; ++dt)
#pragma unroll
                        for (int r = 0; r < 16; ++r) ot[dt][r] *= alpha;
                }
                float rs = 0.0f;
#pragma unroll
                for (int kt = 0; kt < 4; ++kt)
#pragma unroll
                    for (int r = 0; r < 16; ++r) {
                        const float pp = EXP2F(sf[kt][r] - mn);
                        sf[kt][r] = pp;
                        rs += pp;
                    }
                l_run += red32_sum(rs);

                unsigned pc[4][4][2];
#pragma unroll
                for (int kt = 0; kt < 4; ++kt)
#pragma unroll
                    for (int rg = 0; rg < 4; ++rg) {
                        unsigned d0, d1;
                        asm("v_cvt_pk_bf16_f32 %0, %1, %2"
                            : "=v"(d0) : "v"((float)sf[kt][rg * 4 + 0]), "v"((float)sf[kt][rg * 4 + 1]));
                        asm("v_cvt_pk_bf16_f32 %0, %1, %2"
                            : "=v"(d1) : "v"((float)sf[kt][rg * 4 + 2]), "v"((float)sf[kt][rg * 4 + 3]));
                        pc[kt][rg][0] = d0;
                        pc[kt][rg][1] = d1;
                    }

                __builtin_amdgcn_s_setprio(1);
#pragma unroll
                for (int kt = 0; kt < 4; ++kt)
#pragma unroll
                    for (int hh = 0; hh < 2; ++hh) {
                        unsigned a0 = pc[kt][2 * hh][0], a1 = pc[kt][2 * hh][1];
                        unsigned b0 = pc[kt][2 * hh + 1][0], b1 = pc[kt][2 * hh + 1][1];
                        asm("v_permlane32_swap_b32 %0, %1" : "+v"(a0), "+v"(b0));
                        asm("v_permlane32_swap_b32 %0, %1" : "+v"(a1), "+v"(b1));
                        u32x4 wv = {a0, a1, b0, b1};
                        const bf16x8 pb = __builtin_bit_cast(bf16x8, wv);
                        const int k0 = 2 * kt + hh;
#pragma unroll
                        for (int dt = 0; dt < 2; ++dt) {
                            const int d = dt * 32 + lq;
                            const int vswz = ((d & 7) ^ (d >> 3)) & 7;
                            const bf16x8 vf = *(const bf16x8*)&Vb[((d * 128) + (k0 * 16 + lk * 8)) ^ (vswz << 3)];
                            ot[dt] = MFMA32(vf, pb, ot[dt], 0, 0, 0);
                        }
                    }
                __builtin_amdgcn_s_setprio(0);
            }

            asm volatile("s_waitcnt vmcnt(0)" ::: "memory");
            if (t + 1 < nt) {
                u16* const Vn = SM + 16384 + (c ? 0 : 8192);
#pragma unroll
                for (int p = 0; p < 2; ++p) {
                    const int r = w * 16 + p * 8 + rsub;
#pragma unroll
                    for (int i = 0; i < 8; ++i) {
                        const int d = cstage * 8 + i;
                        Vn[((d * 128 + r) ^ (((i ^ cstage) & 7) << 3))] = ((const u16*)&vreg[p])[i];
                    }
                }
            }
            __syncthreads();   // single barrier per tile-step
        }

        // ---- epilogue: O^T -> LDS transpose -> coalesced bf16 stores ----
        u16* const out_l = SM + w * 2176;   // [32][68] per wave (private region)
        const float inv = 1.0f / l_run;
#pragma unroll
        for (int dt = 0; dt < 2; ++dt)
#pragma unroll
            for (int r = 0; r < 16; ++r) {
                const int d = dt * 32 + (r & 3) + 8 * (r >> 2) + 4 * lk;
                out_l[lq * 68 + d] = f32_to_bf16_bits(ot[dt][r] * inv);
            }
#pragma unroll
        for (int rr = 0; rr < 4; ++rr) {
            const int row = rr * 8 + (l >> 3);
            const bf16x8 v = *(const bf16x8*)&out_l[row * 68 + (l & 7) * 8];
            *(bf16x8*)(ctx + (rowbase + qbase + row) * 1024 + h * 64 + (l & 7) * 8) = v;
        }
    }
}

extern "C" void kernel_launch(void* const* d_in, const int* in_sizes, int n_in,
                              void* d_out, int out_size, void* d_ws, size_t ws_size,
                              hipStream_t stream) {
    const float* x      = (const float*)d_in[0];
    const float* W_qkv  = (const float*)d_in[1];
    const float* b_qkv  = (const float*)d_in[2];
    const float* W_o    = (const float*)d_in[3];
    const float* b_o    = (const float*)d_in[4];
    float* out = (float*)d_out;

    const int M = 4 * 2048;     // 8192 rows
    const int C = 1024;
    u16* qkv   = (u16*)d_ws;                       // [8192][3072]
    u16* xb    = qkv   + (size_t)M * 3 * C;        // [8192][1024]
    u16* wqkvt = xb    + (size_t)M * C;            // [3072][1024]
    u16* ctx   = wqkvt + (size_t)3 * C * C;        // [8192][1024]
    u16* wot   = ctx   + (size_t)M * C;            // [1024][1024]

    const float SCQ = 0.125f * 1.44269504089f;     // 1/sqrt(64) * log2(e)

    cvt_bf16_kernel<<<(M * C) / (256 * 8), 256, 0, stream>>>(x, xb, M * C);
    cvt_t2_kernel<<<dim3(3 * C / 64 + C / 64, C / 32), 256, 0, stream>>>(
        W_qkv, wqkvt, 3 * C, W_o, wot, C, C);

    // QKV projection: 8p2 128x256, grid 64*12=768 = 3.0 rounds exactly
    gemm_8p2<1><<<(M / 128) * (3 * C / 256), 512, 0, stream>>>(xb, wqkvt, b_qkv, qkv,
                                                               M, 3 * C, C, C, SCQ);

    attn_kernel<<<256, 512, 0, stream>>>(qkv, ctx);

    // output projection: v2 + supertiled walk, grid 512
    gemm_nt<0><<<(C / 128) * (M / 128), 256, 0, stream>>>(ctx, wot, b_o, out,
                                                          M, C, C, 0, 1.0f, C / 128);
}